// Round 1
// baseline (1056.023 us; speedup 1.0000x reference)
//
#include <hip/hip_runtime.h>

#define C 16
#define TAPS 27

__global__ void make_mask_kernel(const int* __restrict__ mi, float* __restrict__ m, int n) {
    int i = blockIdx.x * blockDim.x + threadIdx.x;
    if (i < n) m[i] = (mi[i] == 0) ? 1.0f : 0.0f;
}

__global__ void pool_mask_kernel(const float* __restrict__ min_, float* __restrict__ mout,
                                 int Din, int Dout) {
    int i = blockIdx.x * blockDim.x + threadIdx.x;
    int n = Dout * Dout * Dout;
    if (i >= n) return;
    int x = i % Dout, y = (i / Dout) % Dout, z = i / (Dout * Dout);
    float v = 0.f;
    for (int kz = 0; kz < 3; kz++) {
        int zz = 2 * z - 1 + kz; if (zz < 0 || zz >= Din) continue;
        for (int ky = 0; ky < 3; ky++) {
            int yy = 2 * y - 1 + ky; if (yy < 0 || yy >= Din) continue;
            for (int kx = 0; kx < 3; kx++) {
                int xx = 2 * x - 1 + kx; if (xx < 0 || xx >= Din) continue;
                v = fmaxf(v, min_[((long)zz * Din + yy) * Din + xx]);
            }
        }
    }
    mout[i] = v;
}

// One thread per output voxel; computes all 16 output channels.
// Weights staged in LDS transposed to [ci][tap][co] so the inner co-loop is
// contiguous; all lanes read the same LDS address (broadcast, conflict-free).
template <int STRIDE>
__global__ void conv_kernel(const float* __restrict__ in, float* __restrict__ out,
                            const float* __restrict__ mask,   // at OUTPUT resolution
                            const float* __restrict__ Wl, const float* __restrict__ bs,
                            const float* __restrict__ bb, int Din, int Dout) {
    __shared__ float wl[C * TAPS * C];
    __shared__ float sc[C], bi[C];
    int tid = threadIdx.x;
    for (int idx = tid; idx < C * C * TAPS; idx += blockDim.x) {
        int co = idx & 15;
        int rest = idx >> 4;
        int tap = rest % TAPS;
        int ci = rest / TAPS;
        wl[idx] = Wl[(co * C + ci) * TAPS + tap];
    }
    if (tid < C) { sc[tid] = bs[tid]; bi[tid] = bb[tid]; }
    __syncthreads();

    long n = (long)Dout * Dout * Dout;
    long v = (long)blockIdx.x * blockDim.x + tid;
    if (v >= n) return;
    int x = (int)(v % Dout);
    int y = (int)((v / Dout) % Dout);
    int z = (int)(v / ((long)Dout * Dout));
    long D3in = (long)Din * Din * Din;

    float mk = mask[v];
    float acc[C];
#pragma unroll
    for (int co = 0; co < C; co++) acc[co] = 0.f;

    if (mk != 0.f) {
        for (int kz = 0; kz < 3; kz++) {
            int zz = STRIDE * z - 1 + kz;
            if (zz < 0 || zz >= Din) continue;
            for (int ky = 0; ky < 3; ky++) {
                int yy = STRIDE * y - 1 + ky;
                if (yy < 0 || yy >= Din) continue;
                for (int kx = 0; kx < 3; kx++) {
                    int xx = STRIDE * x - 1 + kx;
                    if (xx < 0 || xx >= Din) continue;
                    long base = ((long)zz * Din + yy) * Din + xx;
                    const float* wt = &wl[((kz * 3 + ky) * 3 + kx) * C];
#pragma unroll
                    for (int ci = 0; ci < C; ci++) {
                        float vv = in[(long)ci * D3in + base];
                        const float* wp = wt + ci * TAPS * C;
#pragma unroll
                        for (int co = 0; co < C; co++) acc[co] += vv * wp[co];
                    }
                }
            }
        }
    }
#pragma unroll
    for (int co = 0; co < C; co++) {
        float r = fmaxf(acc[co] * sc[co] + bi[co], 0.f) * mk;
        out[(long)co * n + v] = r;
    }
}

extern "C" void kernel_launch(void* const* d_in, const int* in_sizes, int n_in,
                              void* d_out, int out_size, void* d_ws, size_t ws_size,
                              hipStream_t stream) {
    const float* x = (const float*)d_in[0];
    const int* mask_idx = (const int*)d_in[1];
    const float* W = (const float*)d_in[2];
    const float* bs = (const float*)d_in[3];
    const float* bb = (const float*)d_in[4];
    float* out = (float*)d_out;
    float* ws = (float*)d_ws;

    const long D96 = 96, D48 = 48, D24 = 24, D12 = 12, D6 = 6;
    const long n96 = D96 * D96 * D96;      // 884736
    const long n48 = D48 * D48 * D48;      // 110592
    const long n24 = D24 * D24 * D24;      // 13824
    const long n12 = D12 * D12 * D12;      // 1728
    const long n6  = D6 * D6 * D6;         // 216

    float* A = ws;
    float* B = A + C * n96;
    float* m96 = B + C * n96;
    float* m48 = m96 + n96;
    float* m24 = m48 + n48;
    float* m12 = m24 + n24;
    float* m6  = m12 + n12;

    const int BS = 256;
    auto blocks = [&](long n) { return dim3((unsigned)((n + BS - 1) / BS)); };

    // masks
    hipLaunchKernelGGL(make_mask_kernel, blocks(n96), dim3(BS), 0, stream, mask_idx, m96, (int)n96);

    auto subm = [&](const float* in, float* op, const float* m, int layer, int D) {
        long n = (long)D * D * D;
        hipLaunchKernelGGL((conv_kernel<1>), blocks(n), dim3(BS), 0, stream,
                           in, op, m, W + (long)layer * C * C * TAPS,
                           bs + layer * C, bb + layer * C, D, D);
    };
    auto down = [&](const float* in, float* op, const float* m_out, int layer, int Dout) {
        long n = (long)Dout * Dout * Dout;
        hipLaunchKernelGGL((conv_kernel<2>), blocks(n), dim3(BS), 0, stream,
                           in, op, m_out, W + (long)layer * C * C * TAPS,
                           bs + layer * C, bb + layer * C, 2 * Dout, Dout);
    };
    auto pool = [&](const float* mi, float* mo, int Din, int Dout) {
        long n = (long)Dout * Dout * Dout;
        hipLaunchKernelGGL(pool_mask_kernel, blocks(n), dim3(BS), 0, stream, mi, mo, Din, Dout);
    };

    // Stage 0 @96
    subm(x, A, m96, 0, 96);
    subm(A, B, m96, 1, 96);
    // down -> 48
    pool(m96, m48, 96, 48);
    down(B, A, m48, 2, 48);
    subm(A, B, m48, 3, 48);
    subm(B, A, m48, 4, 48);          // net1 in A
    hipMemcpyAsync(out, A, C * n48 * sizeof(float), hipMemcpyDeviceToDevice, stream);
    // down -> 24
    pool(m48, m24, 48, 24);
    down(A, B, m24, 5, 24);
    subm(B, A, m24, 6, 24);
    subm(A, B, m24, 7, 24);
    subm(B, A, m24, 8, 24);          // net2 in A
    hipMemcpyAsync(out + C * n48, A, C * n24 * sizeof(float), hipMemcpyDeviceToDevice, stream);
    // down -> 12
    pool(m24, m12, 24, 12);
    down(A, B, m12, 9, 12);
    subm(B, A, m12, 10, 12);
    subm(A, B, m12, 11, 12);
    subm(B, A, m12, 12, 12);         // net3 in A
    hipMemcpyAsync(out + C * n48 + C * n24, A, C * n12 * sizeof(float), hipMemcpyDeviceToDevice, stream);
    // down -> 6
    pool(m12, m6, 12, 6);
    down(A, B, m6, 13, 6);
    subm(B, A, m6, 14, 6);
    subm(A, B, m6, 15, 6);
    subm(B, A, m6, 16, 6);           // net4 in A
    hipMemcpyAsync(out + C * n48 + C * n24 + C * n12, A, C * n6 * sizeof(float),
                   hipMemcpyDeviceToDevice, stream);
}